// Round 6
// baseline (167.892 us; speedup 1.0000x reference)
//
#include <hip/hip_runtime.h>

// KNN (k=16) within batch-diagonal blocks + neighbor-feature mean-pool.
// N = 16384 points, 8 batches of 2048 (contiguous), FEAT = 16.
//
// R5 -> R6: occupancy was the binding constraint (4 waves/SIMD, grid-capped).
//  * 1024 blocks x 512 threads (8 waves); 16 points/block; 32 segments x 64
//    candidates. lane -> (point = lane&15, seg = wv*4 + (lane>>4)).
//  * LDS: 8-slot/lane candidate buffer (32 KB) + flush(sort-8 -> merge into
//    reg incumbent[16]) => ~34 KB total => 4 blocks/CU = 8 waves/SIMD.
//  * Post-scan: shfl_xor(32) in-register pairwise list merge -> 16 lists/pt,
//    published into reused buffer region ((t+p+s)&15 slot swizzle).
//  * Lane-parallel 16-way merge: lane s = list s, per rank a 4-level
//    shfl_xor argmin; no runtime-indexed register arrays.
//  * Selection exactness unchanged: exact d2 (reference arithmetic) + u64
//    (mono(d2),idx) keys; seed thr = max of 32 disjoint lane-mins (provably
//    valid); conservative margin test only widens the candidate set.

typedef unsigned long long u64;
typedef unsigned int u32;

#define KNN_K 16
#define FEAT 16
#define NWAVE 8
#define THREADS (NWAVE * 64)     // 512
#define BLK_PTS 16
#define SEG_LEN 64               // 2048 / 32 segments
#define NLIST 16                 // lists per point after pairwise premerge
#define BUF_SLOTS 8
#define FLUSH_AT 4               // flush when cnt > 4 (checked every 4 iters)
#define INF_KEY 0xFFFFFFFFFFFFFFFFull

__global__ void knn_prep(const float* __restrict__ y, float4* __restrict__ yp, int m)
{
    const int j = blockIdx.x * 256 + (int)threadIdx.x;
    if (j < m) {
        const float a0 = y[(size_t)j * 3 + 0];
        const float a1 = y[(size_t)j * 3 + 1];
        const float a2 = y[(size_t)j * 3 + 2];
        const float s  = __fadd_rn(__fadd_rn(__fmul_rn(a0, a0), __fmul_rn(a1, a1)),
                                   __fmul_rn(a2, a2));
        yp[j] = make_float4(a0, a1, a2, s);
    }
}

__device__ __forceinline__ u32 mono(float f) {
    const u32 b = __float_as_uint(f);
    return b ^ (((u32)(((int)b) >> 31)) | 0x80000000u);
}

// Sort the lane's 8 buffered keys, merge into sorted incumbent[16].
__device__ __forceinline__ void flush8(u64 (&inc)[16], u64* buf, int lane,
                                       int& cnt, bool& first)
{
    u64 v[8];
#pragma unroll
    for (int t = 0; t < 8; ++t) v[t] = buf[t ^ (lane & 7)];

    // Bitonic sort-8 ascending (static indexing).
#pragma unroll
    for (int k = 2; k <= 8; k <<= 1) {
#pragma unroll
        for (int j = k >> 1; j > 0; j >>= 1) {
#pragma unroll
            for (int a = 0; a < 8; ++a) {
                const int b = a ^ j;
                if (b > a) {
                    const bool up = (a & k) == 0;
                    const u64 va = v[a], vb = v[b];
                    const bool sw = up ? (vb < va) : (va < vb);
                    v[a] = sw ? vb : va;
                    v[b] = sw ? va : vb;
                }
            }
        }
    }

    if (first) {
#pragma unroll
        for (int t = 0; t < 8; ++t)  inc[t] = v[t];
#pragma unroll
        for (int t = 8; t < 16; ++t) inc[t] = INF_KEY;
    } else {
        // Merge sorted-8 (conceptually INF-padded to 16) into sorted inc[16]:
        // half-cleaner m[t] = min(inc[t], v16[15-t]); v16[15-t]=INF for t<8.
#pragma unroll
        for (int t = 8; t < 16; ++t) {
            const u64 a = inc[t], b = v[15 - t];
            inc[t] = (a < b) ? a : b;
        }
        // Clean bitonic 16 -> ascending.
#pragma unroll
        for (int j = 8; j > 0; j >>= 1) {
#pragma unroll
            for (int a = 0; a < 16; ++a) {
                const int b = a ^ j;
                if (b > a) {
                    const u64 va = inc[a], vb = inc[b];
                    const bool sw = vb < va;
                    inc[a] = sw ? vb : va;
                    inc[b] = sw ? va : vb;
                }
            }
        }
    }
    first = false;

#pragma unroll
    for (int t = 0; t < 8; ++t) buf[t] = INF_KEY;
    cnt = 0;
}

__global__ __launch_bounds__(THREADS, 8) void knn_main(
    const float* __restrict__ x, const float4* __restrict__ yp,
    const float* __restrict__ y, const float* __restrict__ feat,
    const int* __restrict__ x_batch, float* __restrict__ out,
    int n, int per, int packed)
{
    __shared__ u64 pu[NWAVE * 64 * BUF_SLOTS];   // 32 KiB: buffers, then lists
    __shared__ u32 idx_s[BLK_PTS * KNN_K];       // 1 KiB winning indices
    __shared__ float thr_s[BLK_PTS];             // seeded thresholds

    const int lane  = (int)threadIdx.x & 63;
    const int wv    = __builtin_amdgcn_readfirstlane((int)(threadIdx.x >> 6));
    const int pbase = blockIdx.x * BLK_PTS;

    const int b     = x_batch[pbase];            // uniform (16 | 2048)
    const int ybase = b * per;

    u64* buf = &pu[(wv * 64 + lane) * BUF_SLOTS];
#pragma unroll
    for (int t = 0; t < BUF_SLOTS; ++t) buf[t] = INF_KEY;

    // ---- Seed: wave wv seeds points wv*2 + (lane>>5); 32-lane groups, each
    // lane min over 32 disjoint samples; thr = max of the 32 lane-mins
    // (>= 32 distinct candidate distances => always a valid prune threshold).
    {
        const int g   = lane >> 5;               // 0..1
        const int l32 = lane & 31;
        const int ps  = pbase + wv * 2 + g;
        const float sx0 = x[(size_t)ps * 3 + 0];
        const float sx1 = x[(size_t)ps * 3 + 1];
        const float sx2 = x[(size_t)ps * 3 + 2];
        const float sx2s = __fadd_rn(__fadd_rn(__fmul_rn(sx0, sx0), __fmul_rn(sx1, sx1)),
                                     __fmul_rn(sx2, sx2));
        float md = __builtin_inff();
        const int jb = ybase + l32 * 64;         // 32 samples, spread coverage
#pragma unroll 4
        for (int t = 0; t < 32; ++t) {
            float q0, q1, q2, qs;
            if (packed) {
                const float4 q = yp[jb + t];
                q0 = q.x; q1 = q.y; q2 = q.z; qs = q.w;
            } else {
                q0 = y[(size_t)(jb + t) * 3 + 0];
                q1 = y[(size_t)(jb + t) * 3 + 1];
                q2 = y[(size_t)(jb + t) * 3 + 2];
                qs = __fadd_rn(__fadd_rn(__fmul_rn(q0, q0), __fmul_rn(q1, q1)),
                               __fmul_rn(q2, q2));
            }
            float dot = __fmaf_rn(sx0, q0, 0.0f);
            dot = __fmaf_rn(sx1, q1, dot);
            dot = __fmaf_rn(sx2, q2, dot);
            const float d2 = __fsub_rn(__fadd_rn(sx2s, qs), __fmul_rn(2.0f, dot));
            md = fminf(md, d2);
        }
#pragma unroll
        for (int mask = 1; mask <= 16; mask <<= 1)
            md = fmaxf(md, __shfl_xor(md, mask));
        if (l32 == 0) thr_s[wv * 2 + g] = md;
    }
    __syncthreads();

    // ---- Scan: point = lane&15, segment = wv*4 + (lane>>4), 64 candidates.
    const int p    = lane & 15;
    const int sgrp = lane >> 4;                  // 0..3
    const int i    = pbase + p;
    const float px0 = x[(size_t)i * 3 + 0];
    const float px1 = x[(size_t)i * 3 + 1];
    const float px2 = x[(size_t)i * 3 + 2];
    const float x2s = __fadd_rn(__fadd_rn(__fmul_rn(px0, px0), __fmul_rn(px1, px1)),
                                __fmul_rn(px2, px2));
    const float thrf = thr_s[p];
    // keep iff dot >= qs*0.5 + C; margin 0.03 >> rounding => never drops a
    // true candidate; extras filtered exactly by the u64 keys.
    const float C = (x2s - thrf) * 0.5f - 0.03f;

    u64 inc[16];
    bool first = true;
    int  cnt   = 0;
    const int jbeg = ybase + (wv * 4 + sgrp) * SEG_LEN;

    for (int j4 = 0; j4 < SEG_LEN; j4 += 4) {
#pragma unroll
        for (int u = 0; u < 4; ++u) {
            const int j = jbeg + j4 + u;
            float q0, q1, q2, qs;
            if (packed) {
                const float4 q = yp[j];
                q0 = q.x; q1 = q.y; q2 = q.z; qs = q.w;
            } else {
                q0 = y[(size_t)j * 3 + 0];
                q1 = y[(size_t)j * 3 + 1];
                q2 = y[(size_t)j * 3 + 2];
                qs = __fadd_rn(__fadd_rn(__fmul_rn(q0, q0), __fmul_rn(q1, q1)),
                               __fmul_rn(q2, q2));
            }
            float dot = __fmaf_rn(px0, q0, 0.0f);
            dot = __fmaf_rn(px1, q1, dot);
            dot = __fmaf_rn(px2, q2, dot);
            const float test = __fmaf_rn(qs, 0.5f, C);
            if (dot >= test) {
                // Exact d2 (reference arithmetic) on the append path only.
                const float d2 = __fsub_rn(__fadd_rn(x2s, qs), __fmul_rn(2.0f, dot));
                buf[cnt ^ (lane & 7)] = ((u64)mono(d2) << 32) | (u32)j;
                cnt++;
            }
        }
        if (__any(cnt > FLUSH_AT)) flush8(inc, buf, lane, cnt, first);
    }
    if (__any(cnt > 0)) flush8(inc, buf, lane, cnt, first);
    if (first) {                                  // no candidate ever appended
#pragma unroll
        for (int t = 0; t < 16; ++t) inc[t] = INF_KEY;
    }

    __syncthreads();   // all scan buffers dead; pu re-used as list store

    // ---- Pairwise premerge with partner lane^32 (disjoint segment): keep
    // low-16 of the merged 32. In-place pair processing avoids a 2nd array.
#pragma unroll
    for (int t = 0; t < 8; ++t) {
        const int uu = 15 - t;
        const u64 ot = __shfl_xor((u64)inc[uu], 32);
        const u64 ou = __shfl_xor((u64)inc[t],  32);
        const u64 a  = (inc[t]  < ot) ? inc[t]  : ot;
        const u64 bb = (inc[uu] < ou) ? inc[uu] : ou;
        inc[t] = a; inc[uu] = bb;
    }
#pragma unroll
    for (int j = 8; j > 0; j >>= 1) {
#pragma unroll
        for (int a = 0; a < 16; ++a) {
            const int b2 = a ^ j;
            if (b2 > a) {
                const u64 va = inc[a], vb = inc[b2];
                const bool sw = vb < va;
                inc[a]  = sw ? vb : va;
                inc[b2] = sw ? va : vb;
            }
        }
    }

    // ---- Publish 16 lists/point (lanes < 32): list id = wv*2 + sgrp.
    if (lane < 32) {
        const int lid = wv * 2 + sgrp;           // sgrp in {0,1} here
        u64* dst = &pu[(p * NLIST + lid) * 16];
#pragma unroll
        for (int t = 0; t < 16; ++t)
            dst[(t + p + lid) & 15] = inc[t];
    }
    __syncthreads();

    // ---- Lane-parallel 16-way merge + gather: lanes<32, 16-lane groups.
    if (lane < 32) {
        const int gp = sgrp;                     // 0..1
        const int s  = lane & 15;                // list id / rank id
        const int pl = wv * 2 + gp;              // local point 0..15

        int h = 0;
#pragma unroll
        for (int r = 0; r < KNN_K; ++r) {
            u64 k = pu[(pl * NLIST + s) * 16 + ((h + pl + s) & 15)];
            int id = lane;
#pragma unroll
            for (int mask = 1; mask <= 8; mask <<= 1) {
                const u64 ok = __shfl_xor((u64)k, mask);
                const int oi = __shfl_xor(id, mask);
                if (ok < k) { k = ok; id = oi; }  // keys unique: no ties
            }
            if (s == 0) idx_s[pl * KNN_K + r] = (u32)k;
            if (lane == id) h++;
        }

        // Gather: lane = (point pl, rank s); butterfly-sum over the 16 ranks.
        const int gidx = (int)idx_s[pl * KNN_K + s];
        const float4* fp = (const float4*)feat + (size_t)gidx * 4;
        const float4 f0 = fp[0], f1 = fp[1], f2 = fp[2], f3 = fp[3];
        float f[FEAT] = { f0.x, f0.y, f0.z, f0.w, f1.x, f1.y, f1.z, f1.w,
                          f2.x, f2.y, f2.z, f2.w, f3.x, f3.y, f3.z, f3.w };
#pragma unroll
        for (int mask = 1; mask <= 8; mask <<= 1) {
#pragma unroll
            for (int c = 0; c < FEAT; ++c)
                f[c] = __fadd_rn(f[c], __shfl_xor(f[c], mask));
        }
        if (s < 4) {
            float4* o4 = (float4*)out + (size_t)(pbase + pl) * 4;
            o4[s] = make_float4(__fmul_rn(f[s * 4 + 0], 0.0625f),
                                __fmul_rn(f[s * 4 + 1], 0.0625f),
                                __fmul_rn(f[s * 4 + 2], 0.0625f),
                                __fmul_rn(f[s * 4 + 3], 0.0625f));
        }
    }
}

extern "C" void kernel_launch(void* const* d_in, const int* in_sizes, int n_in,
                              void* d_out, int out_size, void* d_ws, size_t ws_size,
                              hipStream_t stream) {
    const float* x       = (const float*)d_in[0];
    const float* y       = (const float*)d_in[1];
    const float* feat    = (const float*)d_in[2];
    const int*   x_batch = (const int*)d_in[3];

    const int n   = in_sizes[0] / 3;   // 16384 query points
    const int m   = in_sizes[1] / 3;   // 16384 y points
    const int per = m / 8;             // 2048 per batch (N_BATCHES = 8)

    float* out = (float*)d_out;

    const size_t need = (size_t)m * sizeof(float4);
    const int packed = (ws_size >= need) ? 1 : 0;
    float4* yp = (float4*)d_ws;

    if (packed)
        knn_prep<<<(m + 255) / 256, 256, 0, stream>>>(y, yp, m);

    const int blocks = n / BLK_PTS;    // 1024
    knn_main<<<blocks, THREADS, 0, stream>>>(x, yp, y, feat, x_batch, out,
                                             n, per, packed);
}

// Round 7
// 100.128 us; speedup vs baseline: 1.6768x; 1.6768x over previous
//
#include <hip/hip_runtime.h>

// KNN (k=16) within batch-diagonal blocks + neighbor-feature mean-pool.
// N = 16384 points, 8 batches of 2048 (contiguous), FEAT = 16.
//
// R6 -> R7: R6's __launch_bounds__(512,8) forced VGPR=32 -> inc[16] spilled
// (FETCH 139MB of scratch). R7 gets 8 waves/SIMD WITHOUT squeezing regs:
//  * 512 blocks x 1024 threads (16 waves), 32 points/block; lane ->
//    (point = lane&31, half = lane>>5), segment = wv*2 + half (32 seg x 64).
//  * LDS = 64KB buffer region (8 slots/lane) + thr -> 2 blocks/CU (needs
//    <=80KB) => 32 waves/CU; launch_bounds(1024,4) keeps the R5-proven
//    register budget (~56, no spill); 56<=64 lets HW run 8 waves/SIMD.
//  * flush8: bitonic sort-8 of buffer + merge into sorted reg inc[16].
//  * premerge partner lane^32 (same point, disjoint segment) -> 16 lists/pt,
//    republished into recycled buffer region; lane-parallel 16-way argmin
//    merge (rank-s winner kept in lane s's register, no LDS round-trip).
//  * Selection exactness unchanged (5 passing rounds): exact reference
//    arithmetic d2, u64 (mono(d2),idx) keys, seed thr = max of 16 group-mins
//    over disjoint samples (provably >= 16th-best), conservative margin test.

typedef unsigned long long u64;
typedef unsigned int u32;

#define KNN_K 16
#define FEAT 16
#define NWAVE 16
#define THREADS (NWAVE * 64)     // 1024
#define BLK_PTS 32
#define SEG_LEN 64               // 2048 / 32 segments
#define BUF_SLOTS 8
#define FLUSH_AT 4               // checked every 4 iters; 4+4 <= 8 slots
#define INF_KEY 0xFFFFFFFFFFFFFFFFull

__global__ void knn_prep(const float* __restrict__ y, float4* __restrict__ yp, int m)
{
    const int j = blockIdx.x * 256 + (int)threadIdx.x;
    if (j < m) {
        const float a0 = y[(size_t)j * 3 + 0];
        const float a1 = y[(size_t)j * 3 + 1];
        const float a2 = y[(size_t)j * 3 + 2];
        const float s  = __fadd_rn(__fadd_rn(__fmul_rn(a0, a0), __fmul_rn(a1, a1)),
                                   __fmul_rn(a2, a2));
        yp[j] = make_float4(a0, a1, a2, s);
    }
}

__device__ __forceinline__ u32 mono(float f) {
    const u32 b = __float_as_uint(f);
    return b ^ (((u32)(((int)b) >> 31)) | 0x80000000u);
}

// Sort the lane's 8 buffered keys, merge into sorted incumbent[16].
__device__ __forceinline__ void flush8(u64 (&inc)[16], u64* buf, int lane,
                                       int& cnt, bool& first)
{
    u64 v[8];
#pragma unroll
    for (int t = 0; t < 8; ++t) v[t] = buf[t ^ (lane & 7)];

    // Bitonic sort-8 ascending (static indexing).
#pragma unroll
    for (int k = 2; k <= 8; k <<= 1) {
#pragma unroll
        for (int j = k >> 1; j > 0; j >>= 1) {
#pragma unroll
            for (int a = 0; a < 8; ++a) {
                const int b = a ^ j;
                if (b > a) {
                    const bool up = (a & k) == 0;
                    const u64 va = v[a], vb = v[b];
                    const bool sw = up ? (vb < va) : (va < vb);
                    v[a] = sw ? vb : va;
                    v[b] = sw ? va : vb;
                }
            }
        }
    }

    if (first) {
#pragma unroll
        for (int t = 0; t < 8; ++t)  inc[t] = v[t];
#pragma unroll
        for (int t = 8; t < 16; ++t) inc[t] = INF_KEY;
    } else {
        // Lowest-16 of sorted inc[16] + sorted v[8] (INF-padded to 16):
        // half-cleaner touches only t=8..15, then clean bitonic-16.
#pragma unroll
        for (int t = 8; t < 16; ++t) {
            const u64 a = inc[t], b = v[15 - t];
            inc[t] = (a < b) ? a : b;
        }
#pragma unroll
        for (int j = 8; j > 0; j >>= 1) {
#pragma unroll
            for (int a = 0; a < 16; ++a) {
                const int b = a ^ j;
                if (b > a) {
                    const u64 va = inc[a], vb = inc[b];
                    const bool sw = vb < va;
                    inc[a] = sw ? vb : va;
                    inc[b] = sw ? va : vb;
                }
            }
        }
    }
    first = false;

#pragma unroll
    for (int t = 0; t < 8; ++t) buf[t] = INF_KEY;
    cnt = 0;
}

__global__ __launch_bounds__(THREADS, 4) void knn_main(
    const float* __restrict__ x, const float4* __restrict__ yp,
    const float* __restrict__ y, const float* __restrict__ feat,
    const int* __restrict__ x_batch, float* __restrict__ out,
    int n, int per, int packed)
{
    __shared__ u64 pu[NWAVE * 64 * BUF_SLOTS];   // 64 KiB: buffers, then lists
    __shared__ float thr_s[BLK_PTS];             // seeded thresholds

    const int lane  = (int)threadIdx.x & 63;
    const int wv    = __builtin_amdgcn_readfirstlane((int)(threadIdx.x >> 6));
    const int pbase = blockIdx.x * BLK_PTS;

    const int b     = x_batch[pbase];            // uniform (32 | 2048)
    const int ybase = b * per;

    u64* buf = &pu[(wv * 64 + lane) * BUF_SLOTS];
#pragma unroll
    for (int t = 0; t < BUF_SLOTS; ++t) buf[t] = INF_KEY;

    // ---- Seed: wave wv seeds points wv*2 + (lane>>5). Per point: 16 groups
    // (lane pairs) x 32 disjoint samples; thr = max of the 16 group-mins
    // (>= 16 distinct candidate distances => always a valid prune threshold).
    {
        const int g   = lane >> 5;               // 0..1
        const int l32 = lane & 31;
        const int ps  = pbase + wv * 2 + g;
        const float sx0 = x[(size_t)ps * 3 + 0];
        const float sx1 = x[(size_t)ps * 3 + 1];
        const float sx2 = x[(size_t)ps * 3 + 2];
        const float sx2s = __fadd_rn(__fadd_rn(__fmul_rn(sx0, sx0), __fmul_rn(sx1, sx1)),
                                     __fmul_rn(sx2, sx2));
        float md = __builtin_inff();
        const int jb = ybase + l32 * 64;         // lane's 16 samples, stride 4
#pragma unroll 4
        for (int t = 0; t < 16; ++t) {
            const int j = jb + t * 4;
            float q0, q1, q2, qs;
            if (packed) {
                const float4 q = yp[j];
                q0 = q.x; q1 = q.y; q2 = q.z; qs = q.w;
            } else {
                q0 = y[(size_t)j * 3 + 0];
                q1 = y[(size_t)j * 3 + 1];
                q2 = y[(size_t)j * 3 + 2];
                qs = __fadd_rn(__fadd_rn(__fmul_rn(q0, q0), __fmul_rn(q1, q1)),
                               __fmul_rn(q2, q2));
            }
            float dot = __fmaf_rn(sx0, q0, 0.0f);
            dot = __fmaf_rn(sx1, q1, dot);
            dot = __fmaf_rn(sx2, q2, dot);
            const float d2 = __fsub_rn(__fadd_rn(sx2s, qs), __fmul_rn(2.0f, dot));
            md = fminf(md, d2);
        }
        md = fminf(md, __shfl_xor(md, 1));       // group-min (2 lanes x 16)
#pragma unroll
        for (int mask = 2; mask <= 16; mask <<= 1)
            md = fmaxf(md, __shfl_xor(md, mask)); // max over 16 groups
        if (l32 == 0) thr_s[wv * 2 + g] = md;
    }
    __syncthreads();

    // ---- Scan: point = lane&31, segment = wv*2 + (lane>>5), 64 candidates.
    const int p = lane & 31;
    const int i = pbase + p;
    const float px0 = x[(size_t)i * 3 + 0];
    const float px1 = x[(size_t)i * 3 + 1];
    const float px2 = x[(size_t)i * 3 + 2];
    const float x2s = __fadd_rn(__fadd_rn(__fmul_rn(px0, px0), __fmul_rn(px1, px1)),
                                __fmul_rn(px2, px2));
    const float thrf = thr_s[p];
    // keep iff dot >= qs*0.5 + C; margin 0.03 >> rounding => never drops a
    // true candidate; extras filtered exactly by the u64 keys.
    const float C = (x2s - thrf) * 0.5f - 0.03f;

    u64 inc[16];
    bool first = true;
    int  cnt   = 0;
    const int jbeg = ybase + (wv * 2 + (lane >> 5)) * SEG_LEN;

    for (int j4 = 0; j4 < SEG_LEN; j4 += 4) {
#pragma unroll
        for (int u = 0; u < 4; ++u) {
            const int j = jbeg + j4 + u;
            float q0, q1, q2, qs;
            if (packed) {
                const float4 q = yp[j];
                q0 = q.x; q1 = q.y; q2 = q.z; qs = q.w;
            } else {
                q0 = y[(size_t)j * 3 + 0];
                q1 = y[(size_t)j * 3 + 1];
                q2 = y[(size_t)j * 3 + 2];
                qs = __fadd_rn(__fadd_rn(__fmul_rn(q0, q0), __fmul_rn(q1, q1)),
                               __fmul_rn(q2, q2));
            }
            float dot = __fmaf_rn(px0, q0, 0.0f);
            dot = __fmaf_rn(px1, q1, dot);
            dot = __fmaf_rn(px2, q2, dot);
            const float test = __fmaf_rn(qs, 0.5f, C);
            if (dot >= test) {
                // Exact d2 (reference arithmetic) on the append path only.
                const float d2 = __fsub_rn(__fadd_rn(x2s, qs), __fmul_rn(2.0f, dot));
                buf[cnt ^ (lane & 7)] = ((u64)mono(d2) << 32) | (u32)j;
                cnt++;
            }
        }
        if (__any(cnt > FLUSH_AT)) flush8(inc, buf, lane, cnt, first);
    }
    if (__any(cnt > 0)) flush8(inc, buf, lane, cnt, first);
    if (first) {
#pragma unroll
        for (int t = 0; t < 16; ++t) inc[t] = INF_KEY;
    }

    __syncthreads();   // all scan buffers dead; pu re-used as list store

    // ---- Premerge with partner lane^32 (same point, disjoint segment):
    // keep low-16 of the merged 32 (both partners compute the same result).
#pragma unroll
    for (int t = 0; t < 8; ++t) {
        const int uu = 15 - t;
        const u64 ot = __shfl_xor((u64)inc[uu], 32);
        const u64 ou = __shfl_xor((u64)inc[t],  32);
        const u64 a  = (inc[t]  < ot) ? inc[t]  : ot;
        const u64 bb = (inc[uu] < ou) ? inc[uu] : ou;
        inc[t] = a; inc[uu] = bb;
    }
#pragma unroll
    for (int j = 8; j > 0; j >>= 1) {
#pragma unroll
        for (int a = 0; a < 16; ++a) {
            const int b2 = a ^ j;
            if (b2 > a) {
                const u64 va = inc[a], vb = inc[b2];
                const bool sw = vb < va;
                inc[a]  = sw ? vb : va;
                inc[b2] = sw ? va : vb;
            }
        }
    }

    // ---- Publish 16 lists/point (lanes < 32): list id = wv.
    if (lane < 32) {
        u64* dst = &pu[(p * 16 + wv) * 16];
#pragma unroll
        for (int t = 0; t < 16; ++t)
            dst[(t + p + wv) & 15] = inc[t];
    }
    __syncthreads();

    // ---- Lane-parallel 16-way merge + gather: lanes<32, 16-lane groups.
    if (lane < 32) {
        const int pl = wv * 2 + (lane >> 4);     // local point 0..31
        const int s  = lane & 15;                // list id / rank id

        int h = 0;
        u64 myk = INF_KEY;
#pragma unroll
        for (int r = 0; r < KNN_K; ++r) {
            u64 k = pu[(pl * 16 + s) * 16 + ((h + pl + s) & 15)];
            int id = lane;
#pragma unroll
            for (int mask = 1; mask <= 8; mask <<= 1) {
                const u64 ok = __shfl_xor((u64)k, mask);
                const int oi = __shfl_xor(id, mask);
                if (ok < k) { k = ok; id = oi; }  // keys unique: no ties
            }
            if (r == s) myk = k;                  // rank-s winner stays here
            if (lane == id) h++;
        }

        // Gather: lane = (point pl, rank s); butterfly-sum over the 16 ranks.
        const int gidx = (int)(u32)myk;
        const float4* fp = (const float4*)feat + (size_t)gidx * 4;
        const float4 f0 = fp[0], f1 = fp[1], f2 = fp[2], f3 = fp[3];
        float f[FEAT] = { f0.x, f0.y, f0.z, f0.w, f1.x, f1.y, f1.z, f1.w,
                          f2.x, f2.y, f2.z, f2.w, f3.x, f3.y, f3.z, f3.w };
#pragma unroll
        for (int mask = 1; mask <= 8; mask <<= 1) {
#pragma unroll
            for (int c = 0; c < FEAT; ++c)
                f[c] = __fadd_rn(f[c], __shfl_xor(f[c], mask));
        }
        if (s < 4) {
            float4* o4 = (float4*)out + (size_t)(pbase + pl) * 4;
            o4[s] = make_float4(__fmul_rn(f[s * 4 + 0], 0.0625f),
                                __fmul_rn(f[s * 4 + 1], 0.0625f),
                                __fmul_rn(f[s * 4 + 2], 0.0625f),
                                __fmul_rn(f[s * 4 + 3], 0.0625f));
        }
    }
}

extern "C" void kernel_launch(void* const* d_in, const int* in_sizes, int n_in,
                              void* d_out, int out_size, void* d_ws, size_t ws_size,
                              hipStream_t stream) {
    const float* x       = (const float*)d_in[0];
    const float* y       = (const float*)d_in[1];
    const float* feat    = (const float*)d_in[2];
    const int*   x_batch = (const int*)d_in[3];

    const int n   = in_sizes[0] / 3;   // 16384 query points
    const int m   = in_sizes[1] / 3;   // 16384 y points
    const int per = m / 8;             // 2048 per batch (N_BATCHES = 8)

    float* out = (float*)d_out;

    const size_t need = (size_t)m * sizeof(float4);
    const int packed = (ws_size >= need) ? 1 : 0;
    float4* yp = (float4*)d_ws;

    if (packed)
        knn_prep<<<(m + 255) / 256, 256, 0, stream>>>(y, yp, m);

    const int blocks = n / BLK_PTS;    // 512 = 2 blocks/CU
    knn_main<<<blocks, THREADS, 0, stream>>>(x, yp, y, feat, x_batch, out,
                                             n, per, packed);
}

// Round 8
// 62.724 us; speedup vs baseline: 2.6767x; 1.5963x over previous
//
#include <hip/hip_runtime.h>

// KNN (k=16) within batch-diagonal blocks + neighbor-feature mean-pool.
// N = 16384 points, 8 batches of 2048 (contiguous), FEAT = 16.
//
// R7 -> R8: one wave = one point; no segments, no flush machinery, no
// __syncthreads. Per wave (point i):
//   A: lane-min d2 over 32 disjoint candidates (coalesced float4 loads).
//   thr = 16th-smallest of the 64 lane-mins (wave bitonic sort-64, u32
//      mono keys). Valid: 16 smallest lane-mins are 16 distinct candidates
//      <= thr => true 16th-best <= thr => top-16 all survive phase B.
//   B: rescan (bit-identical d2: same ops, same inputs), append survivors
//      (mono(d2)<<32 | j) to per-wave LDS list via DS atomic counter.
//      E[S] ~ 18; hard bound handled to 512 exactly.
//   C: wave bitonic sort-64 of survivors (u64 keys unique; low-bits idx =
//      lax.top_k stable tie order => selection EXACT); chunked re-sort
//      covers S>64 exactly. Lanes 0..15 = top-16 -> gather + butterfly mean
//      (sum-order relaxation proven in R4, rounding-only, ~1e-6 << 2.2e-2).
// Distance arithmetic bit-identical to R1-R7 (all passed):
//   dot = ascending-k FMA chain; x2/y2 = rounded squares + sequential adds;
//   d2  = (x2 + y2) - 2*dot.

typedef unsigned long long u64;
typedef unsigned int u32;

#define FEAT 16
#define BLK_WAVES 8
#define THREADS (BLK_WAVES * 64)   // 512
#define LIST_CAP 512
#define INF_KEY 0xFFFFFFFFFFFFFFFFull

__global__ void knn_prep(const float* __restrict__ y, float4* __restrict__ yp, int m)
{
    const int j = blockIdx.x * 256 + (int)threadIdx.x;
    if (j < m) {
        const float a0 = y[(size_t)j * 3 + 0];
        const float a1 = y[(size_t)j * 3 + 1];
        const float a2 = y[(size_t)j * 3 + 2];
        const float s  = __fadd_rn(__fadd_rn(__fmul_rn(a0, a0), __fmul_rn(a1, a1)),
                                   __fmul_rn(a2, a2));
        yp[j] = make_float4(a0, a1, a2, s);
    }
}

__device__ __forceinline__ u32 mono(float f) {
    const u32 b = __float_as_uint(f);
    return b ^ (((u32)(((int)b) >> 31)) | 0x80000000u);
}
__device__ __forceinline__ float unmono(u32 h) {
    const u32 b = (h & 0x80000000u) ? (h & 0x7FFFFFFFu) : ~h;
    return __uint_as_float(b);
}

// Cross-lane bitonic sort over the 64 lanes, ascending by lane index.
__device__ __forceinline__ u32 sort64_u32(u32 k, int lane) {
#pragma unroll
    for (int kk = 2; kk <= 64; kk <<= 1) {
#pragma unroll
        for (int j = kk >> 1; j > 0; j >>= 1) {
            const u32 o = __shfl_xor(k, j);
            const bool keep_min = (((lane & j) == 0) == ((lane & kk) == 0));
            const u32 mn = (k < o) ? k : o;
            const u32 mx = (k < o) ? o : k;
            k = keep_min ? mn : mx;
        }
    }
    return k;
}
__device__ __forceinline__ u64 sort64_u64(u64 k, int lane) {
#pragma unroll
    for (int kk = 2; kk <= 64; kk <<= 1) {
#pragma unroll
        for (int j = kk >> 1; j > 0; j >>= 1) {
            const u64 o = __shfl_xor(k, j);
            const bool keep_min = (((lane & j) == 0) == ((lane & kk) == 0));
            const u64 mn = (k < o) ? k : o;
            const u64 mx = (k < o) ? o : k;
            k = keep_min ? mn : mx;
        }
    }
    return k;
}

__global__ __launch_bounds__(THREADS, 8) void knn_main(
    const float* __restrict__ x, const float4* __restrict__ yp,
    const float* __restrict__ y, const float* __restrict__ feat,
    const int* __restrict__ x_batch, float* __restrict__ out,
    int n, int per, int packed)
{
    __shared__ u64 list_s[BLK_WAVES][LIST_CAP];  // 32 KiB survivor lists
    __shared__ int cnt_s[BLK_WAVES];

    const int lane = (int)threadIdx.x & 63;
    const int wv   = (int)(threadIdx.x >> 6);
    const int i    = blockIdx.x * BLK_WAVES + wv;   // this wave's point
    if (i >= n) return;

    if (lane == 0) cnt_s[wv] = 0;   // own counter; same-wave DS is in-order

    const int b     = x_batch[i];                   // lane-uniform
    const int ybase = b * per;

    const float px0 = x[(size_t)i * 3 + 0];
    const float px1 = x[(size_t)i * 3 + 1];
    const float px2 = x[(size_t)i * 3 + 2];
    const float x2s = __fadd_rn(__fadd_rn(__fmul_rn(px0, px0), __fmul_rn(px1, px1)),
                                __fmul_rn(px2, px2));

    const int iters = per / 64;                     // 32

    // ---- Phase A: lane-min d2 over candidates j = ybase + t*64 + lane.
    float md = __builtin_inff();
    for (int t = 0; t < iters; ++t) {
        const int j = ybase + t * 64 + lane;        // coalesced across lanes
        float q0, q1, q2, qs;
        if (packed) {
            const float4 q = yp[j];
            q0 = q.x; q1 = q.y; q2 = q.z; qs = q.w;
        } else {
            q0 = y[(size_t)j * 3 + 0];
            q1 = y[(size_t)j * 3 + 1];
            q2 = y[(size_t)j * 3 + 2];
            qs = __fadd_rn(__fadd_rn(__fmul_rn(q0, q0), __fmul_rn(q1, q1)),
                           __fmul_rn(q2, q2));
        }
        float dot = __fmaf_rn(px0, q0, 0.0f);
        dot = __fmaf_rn(px1, q1, dot);
        dot = __fmaf_rn(px2, q2, dot);
        const float d2 = __fsub_rn(__fadd_rn(x2s, qs), __fmul_rn(2.0f, dot));
        md = fminf(md, d2);
    }

    // thr = 16th-smallest of the 64 lane-mins (exact d2 bits).
    const u32 sorted = sort64_u32(mono(md), lane);
    const float thrf = unmono(__shfl(sorted, 15));

    // ---- Phase B: rescan (bit-identical d2), append survivors.
    for (int t = 0; t < iters; ++t) {
        const int j = ybase + t * 64 + lane;
        float q0, q1, q2, qs;
        if (packed) {
            const float4 q = yp[j];
            q0 = q.x; q1 = q.y; q2 = q.z; qs = q.w;
        } else {
            q0 = y[(size_t)j * 3 + 0];
            q1 = y[(size_t)j * 3 + 1];
            q2 = y[(size_t)j * 3 + 2];
            qs = __fadd_rn(__fadd_rn(__fmul_rn(q0, q0), __fmul_rn(q1, q1)),
                           __fmul_rn(q2, q2));
        }
        float dot = __fmaf_rn(px0, q0, 0.0f);
        dot = __fmaf_rn(px1, q1, dot);
        dot = __fmaf_rn(px2, q2, dot);
        const float d2 = __fsub_rn(__fadd_rn(x2s, qs), __fmul_rn(2.0f, dot));
        if (d2 <= thrf) {
            const int slot = atomicAdd(&cnt_s[wv], 1);
            if (slot < LIST_CAP)
                list_s[wv][slot] = ((u64)mono(d2) << 32) | (u32)j;
        }
    }

    int S = *(volatile int*)&cnt_s[wv];             // same-wave DS in-order
    if (S > LIST_CAP) S = LIST_CAP;

    // ---- Phase C: top-16 via wave sort-64 (chunked for S > 64; exact).
    u64 k0 = (lane < S) ? list_s[wv][lane] : INF_KEY;
    u64 top = sort64_u64(k0, lane);
    for (int pos = 64; pos < S; pos += 48) {
        const int src = pos + lane - 16;
        const u64 k = (lane < 16) ? top
                                  : ((src < S) ? list_s[wv][src] : INF_KEY);
        top = sort64_u64(k, lane);
    }

    // ---- Gather + mean: lanes 0..15 hold ranks 0..15 (sorted, exact order).
    if (lane < 16) {
        const int gidx = (int)(u32)top;             // global y index
        const float4* fp = (const float4*)feat + (size_t)gidx * 4;
        const float4 f0 = fp[0], f1 = fp[1], f2 = fp[2], f3 = fp[3];
        float f[FEAT] = { f0.x, f0.y, f0.z, f0.w, f1.x, f1.y, f1.z, f1.w,
                          f2.x, f2.y, f2.z, f2.w, f3.x, f3.y, f3.z, f3.w };
#pragma unroll
        for (int mask = 1; mask <= 8; mask <<= 1) {  // stays within lanes 0..15
#pragma unroll
            for (int c = 0; c < FEAT; ++c)
                f[c] = __fadd_rn(f[c], __shfl_xor(f[c], mask));
        }
        if (lane < 4) {
            float4* o4 = (float4*)out + (size_t)i * 4;
            o4[lane] = make_float4(__fmul_rn(f[lane * 4 + 0], 0.0625f),
                                   __fmul_rn(f[lane * 4 + 1], 0.0625f),
                                   __fmul_rn(f[lane * 4 + 2], 0.0625f),
                                   __fmul_rn(f[lane * 4 + 3], 0.0625f));
        }
    }
}

extern "C" void kernel_launch(void* const* d_in, const int* in_sizes, int n_in,
                              void* d_out, int out_size, void* d_ws, size_t ws_size,
                              hipStream_t stream) {
    const float* x       = (const float*)d_in[0];
    const float* y       = (const float*)d_in[1];
    const float* feat    = (const float*)d_in[2];
    const int*   x_batch = (const int*)d_in[3];

    const int n   = in_sizes[0] / 3;   // 16384 query points
    const int m   = in_sizes[1] / 3;   // 16384 y points
    const int per = m / 8;             // 2048 per batch (N_BATCHES = 8)

    float* out = (float*)d_out;

    const size_t need = (size_t)m * sizeof(float4);
    const int packed = (ws_size >= need) ? 1 : 0;
    float4* yp = (float4*)d_ws;

    if (packed)
        knn_prep<<<(m + 255) / 256, 256, 0, stream>>>(y, yp, m);

    const int blocks = (n + BLK_WAVES - 1) / BLK_WAVES;   // 2048
    knn_main<<<blocks, THREADS, 0, stream>>>(x, yp, y, feat, x_batch, out,
                                             n, per, packed);
}

// Round 9
// 58.311 us; speedup vs baseline: 2.8793x; 1.0757x over previous
//
#include <hip/hip_runtime.h>

// KNN (k=16) within batch-diagonal blocks + neighbor-feature mean-pool.
// N = 16384 points, 8 batches of 2048 (contiguous), FEAT = 16.
//
// R8 -> R9:
//  * Phase A register-caches all 32 per-lane d2 values (full unroll,
//    compile-time ITERS=32, static indexing) -> Phase B is an in-register
//    test + rare LDS append: no reload, no distance recompute. Cached bits
//    are THE phase-A bits => exactness argument unchanged.
//  * Gather uses all 64 lanes: lane=(rank=lane&15, chunk=lane>>4), one
//    float4 load each, 4-level butterfly (16 shfls), 4 stores.
//  * Everything else identical to R8 (passed, 62.7us): thr = 16th-smallest
//    of the 64 lane-mins (valid: 16 distinct candidates <= thr), survivor
//    list + wave bitonic sort-64 on u64 (mono(d2)<<32|idx) keys = exact
//    lax.top_k order; butterfly mean rounding relaxation proven since R4.

typedef unsigned long long u64;
typedef unsigned int u32;

#define FEAT 16
#define BLK_WAVES 8
#define THREADS (BLK_WAVES * 64)   // 512
#define LIST_CAP 512
#define INF_KEY 0xFFFFFFFFFFFFFFFFull

__global__ void knn_prep(const float* __restrict__ y, float4* __restrict__ yp, int m)
{
    const int j = blockIdx.x * 256 + (int)threadIdx.x;
    if (j < m) {
        const float a0 = y[(size_t)j * 3 + 0];
        const float a1 = y[(size_t)j * 3 + 1];
        const float a2 = y[(size_t)j * 3 + 2];
        const float s  = __fadd_rn(__fadd_rn(__fmul_rn(a0, a0), __fmul_rn(a1, a1)),
                                   __fmul_rn(a2, a2));
        yp[j] = make_float4(a0, a1, a2, s);
    }
}

__device__ __forceinline__ u32 mono(float f) {
    const u32 b = __float_as_uint(f);
    return b ^ (((u32)(((int)b) >> 31)) | 0x80000000u);
}
__device__ __forceinline__ float unmono(u32 h) {
    const u32 b = (h & 0x80000000u) ? (h & 0x7FFFFFFFu) : ~h;
    return __uint_as_float(b);
}

// Cross-lane bitonic sort over the 64 lanes, ascending by lane index.
__device__ __forceinline__ u32 sort64_u32(u32 k, int lane) {
#pragma unroll
    for (int kk = 2; kk <= 64; kk <<= 1) {
#pragma unroll
        for (int j = kk >> 1; j > 0; j >>= 1) {
            const u32 o = __shfl_xor(k, j);
            const bool keep_min = (((lane & j) == 0) == ((lane & kk) == 0));
            const u32 mn = (k < o) ? k : o;
            const u32 mx = (k < o) ? o : k;
            k = keep_min ? mn : mx;
        }
    }
    return k;
}
__device__ __forceinline__ u64 sort64_u64(u64 k, int lane) {
#pragma unroll
    for (int kk = 2; kk <= 64; kk <<= 1) {
#pragma unroll
        for (int j = kk >> 1; j > 0; j >>= 1) {
            const u64 o = __shfl_xor(k, j);
            const bool keep_min = (((lane & j) == 0) == ((lane & kk) == 0));
            const u64 mn = (k < o) ? k : o;
            const u64 mx = (k < o) ? o : k;
            k = keep_min ? mn : mx;
        }
    }
    return k;
}

// CITERS > 0: compile-time candidate count per lane (register d2 cache).
// CITERS == 0: generic runtime fallback (R8's two-pass structure).
template <int CITERS>
__global__ __launch_bounds__(THREADS, 8) void knn_main(
    const float* __restrict__ x, const float4* __restrict__ yp,
    const float* __restrict__ y, const float* __restrict__ feat,
    const int* __restrict__ x_batch, float* __restrict__ out,
    int n, int per, int packed)
{
    __shared__ u64 list_s[BLK_WAVES][LIST_CAP];  // 32 KiB survivor lists
    __shared__ int cnt_s[BLK_WAVES];

    const int lane = (int)threadIdx.x & 63;
    const int wv   = (int)(threadIdx.x >> 6);
    const int i    = blockIdx.x * BLK_WAVES + wv;   // this wave's point
    if (i >= n) return;

    if (lane == 0) cnt_s[wv] = 0;   // own counter; same-wave DS is in-order

    const int b     = x_batch[i];                   // lane-uniform
    const int ybase = b * per;

    const float px0 = x[(size_t)i * 3 + 0];
    const float px1 = x[(size_t)i * 3 + 1];
    const float px2 = x[(size_t)i * 3 + 2];
    const float x2s = __fadd_rn(__fadd_rn(__fmul_rn(px0, px0), __fmul_rn(px1, px1)),
                                __fmul_rn(px2, px2));

    float thrf;

    if constexpr (CITERS > 0) {
        // ---- Phase A: d2 for candidates j = ybase + t*64 + lane, cached.
        float d2c[CITERS];
        float md = __builtin_inff();
#pragma unroll
        for (int t = 0; t < CITERS; ++t) {
            const float4 q = yp[ybase + t * 64 + lane];   // coalesced
            float dot = __fmaf_rn(px0, q.x, 0.0f);
            dot = __fmaf_rn(px1, q.y, dot);
            dot = __fmaf_rn(px2, q.z, dot);
            const float d2 = __fsub_rn(__fadd_rn(x2s, q.w), __fmul_rn(2.0f, dot));
            d2c[t] = d2;
            md = fminf(md, d2);
        }

        // thr = 16th-smallest of the 64 lane-mins (exact d2 bits).
        const u32 sorted = sort64_u32(mono(md), lane);
        thrf = unmono(__shfl(sorted, 15));

        // ---- Phase B: in-register test, append survivors (exact bits).
#pragma unroll
        for (int t = 0; t < CITERS; ++t) {
            if (d2c[t] <= thrf) {
                const int slot = atomicAdd(&cnt_s[wv], 1);
                if (slot < LIST_CAP)
                    list_s[wv][slot] =
                        ((u64)mono(d2c[t]) << 32) | (u32)(ybase + t * 64 + lane);
            }
        }
    } else {
        // Generic fallback: two-pass scan (R8 structure).
        const int iters = per / 64;
        float md = __builtin_inff();
        for (int t = 0; t < iters; ++t) {
            const int j = ybase + t * 64 + lane;
            float q0, q1, q2, qs;
            if (packed) {
                const float4 q = yp[j];
                q0 = q.x; q1 = q.y; q2 = q.z; qs = q.w;
            } else {
                q0 = y[(size_t)j * 3 + 0];
                q1 = y[(size_t)j * 3 + 1];
                q2 = y[(size_t)j * 3 + 2];
                qs = __fadd_rn(__fadd_rn(__fmul_rn(q0, q0), __fmul_rn(q1, q1)),
                               __fmul_rn(q2, q2));
            }
            float dot = __fmaf_rn(px0, q0, 0.0f);
            dot = __fmaf_rn(px1, q1, dot);
            dot = __fmaf_rn(px2, q2, dot);
            md = fminf(md, __fsub_rn(__fadd_rn(x2s, qs), __fmul_rn(2.0f, dot)));
        }
        const u32 sorted = sort64_u32(mono(md), lane);
        thrf = unmono(__shfl(sorted, 15));
        for (int t = 0; t < iters; ++t) {
            const int j = ybase + t * 64 + lane;
            float q0, q1, q2, qs;
            if (packed) {
                const float4 q = yp[j];
                q0 = q.x; q1 = q.y; q2 = q.z; qs = q.w;
            } else {
                q0 = y[(size_t)j * 3 + 0];
                q1 = y[(size_t)j * 3 + 1];
                q2 = y[(size_t)j * 3 + 2];
                qs = __fadd_rn(__fadd_rn(__fmul_rn(q0, q0), __fmul_rn(q1, q1)),
                               __fmul_rn(q2, q2));
            }
            float dot = __fmaf_rn(px0, q0, 0.0f);
            dot = __fmaf_rn(px1, q1, dot);
            dot = __fmaf_rn(px2, q2, dot);
            const float d2 = __fsub_rn(__fadd_rn(x2s, qs), __fmul_rn(2.0f, dot));
            if (d2 <= thrf) {
                const int slot = atomicAdd(&cnt_s[wv], 1);
                if (slot < LIST_CAP)
                    list_s[wv][slot] = ((u64)mono(d2) << 32) | (u32)j;
            }
        }
    }

    int S = *(volatile int*)&cnt_s[wv];             // same-wave DS in-order
    if (S > LIST_CAP) S = LIST_CAP;

    // ---- Phase C: top-16 via wave sort-64 (chunked for S > 64; exact).
    u64 k0 = (lane < S) ? list_s[wv][lane] : INF_KEY;
    u64 top = sort64_u64(k0, lane);
    for (int pos = 64; pos < S; pos += 48) {
        const int src = pos + lane - 16;
        const u64 k = (lane < 16) ? top
                                  : ((src < S) ? list_s[wv][src] : INF_KEY);
        top = sort64_u64(k, lane);
    }

    // ---- Gather + mean, all 64 lanes: rank = lane&15, chunk = lane>>4.
    const int r = lane & 15;
    const int c = lane >> 4;
    const u64 krank = __shfl(top, r);               // rank-r key (lanes 0..15)
    const int gidx  = (int)(u32)krank;              // global y index
    const float4 fq = ((const float4*)feat)[(size_t)gidx * 4 + c];
    float f0 = fq.x, f1 = fq.y, f2 = fq.z, f3 = fq.w;
#pragma unroll
    for (int mask = 1; mask <= 8; mask <<= 1) {     // sum over ranks in-group
        f0 = __fadd_rn(f0, __shfl_xor(f0, mask));
        f1 = __fadd_rn(f1, __shfl_xor(f1, mask));
        f2 = __fadd_rn(f2, __shfl_xor(f2, mask));
        f3 = __fadd_rn(f3, __shfl_xor(f3, mask));
    }
    if (r == 0) {
        float4* o4 = (float4*)out + (size_t)i * 4;
        o4[c] = make_float4(__fmul_rn(f0, 0.0625f), __fmul_rn(f1, 0.0625f),
                            __fmul_rn(f2, 0.0625f), __fmul_rn(f3, 0.0625f));
    }
}

extern "C" void kernel_launch(void* const* d_in, const int* in_sizes, int n_in,
                              void* d_out, int out_size, void* d_ws, size_t ws_size,
                              hipStream_t stream) {
    const float* x       = (const float*)d_in[0];
    const float* y       = (const float*)d_in[1];
    const float* feat    = (const float*)d_in[2];
    const int*   x_batch = (const int*)d_in[3];

    const int n   = in_sizes[0] / 3;   // 16384 query points
    const int m   = in_sizes[1] / 3;   // 16384 y points
    const int per = m / 8;             // 2048 per batch (N_BATCHES = 8)

    float* out = (float*)d_out;

    const size_t need = (size_t)m * sizeof(float4);
    const int packed = (ws_size >= need) ? 1 : 0;
    float4* yp = (float4*)d_ws;

    if (packed)
        knn_prep<<<(m + 255) / 256, 256, 0, stream>>>(y, yp, m);

    const int blocks = (n + BLK_WAVES - 1) / BLK_WAVES;   // 2048
    if (packed && per == 2048)
        knn_main<32><<<blocks, THREADS, 0, stream>>>(x, yp, y, feat, x_batch,
                                                     out, n, per, packed);
    else
        knn_main<0><<<blocks, THREADS, 0, stream>>>(x, yp, y, feat, x_batch,
                                                    out, n, per, packed);
}

// Round 10
// 48.638 us; speedup vs baseline: 3.4519x; 1.1989x over previous
//
#include <hip/hip_runtime.h>

// KNN (k=16) within batch-diagonal blocks + neighbor-feature mean-pool.
// N = 16384 points, 8 batches of 2048 (contiguous), FEAT = 16.
//
// R9 -> R10: R9's d2c[32] cache broke the 64-VGPR cap of
// __launch_bounds__(512,8) -> whole array spilled to scratch (WRITE_SIZE
// 99MB, HBM 2.2TB/s). R10 caches HALF (d2c[16], t=0..15) in registers and
// recomputes t=16..31 in phase B from yp (L1/L2-hot; identical op sequence
// with __f*_rn => bit-identical d2 — R8's proven two-pass structure).
// ~48-56 VGPR => stays at 8 waves/SIMD with zero scratch.
//
// Exactness machinery unchanged (8 passing rounds):
//   thr = 16th-smallest of the 64 lane-mins (16 distinct candidates <= thr
//   => true top-16 survives); survivors -> per-wave LDS list -> wave bitonic
//   sort-64 on u64 (mono(d2)<<32|idx) keys == lax.top_k stable order;
//   distance arithmetic = reference bit pattern (FMA chain, rounded squares);
//   butterfly mean rounding relaxation proven since R4 (~1e-6 << 2.2e-2).

typedef unsigned long long u64;
typedef unsigned int u32;

#define FEAT 16
#define BLK_WAVES 8
#define THREADS (BLK_WAVES * 64)   // 512
#define LIST_CAP 512
#define INF_KEY 0xFFFFFFFFFFFFFFFFull

__global__ void knn_prep(const float* __restrict__ y, float4* __restrict__ yp, int m)
{
    const int j = blockIdx.x * 256 + (int)threadIdx.x;
    if (j < m) {
        const float a0 = y[(size_t)j * 3 + 0];
        const float a1 = y[(size_t)j * 3 + 1];
        const float a2 = y[(size_t)j * 3 + 2];
        const float s  = __fadd_rn(__fadd_rn(__fmul_rn(a0, a0), __fmul_rn(a1, a1)),
                                   __fmul_rn(a2, a2));
        yp[j] = make_float4(a0, a1, a2, s);
    }
}

__device__ __forceinline__ u32 mono(float f) {
    const u32 b = __float_as_uint(f);
    return b ^ (((u32)(((int)b) >> 31)) | 0x80000000u);
}
__device__ __forceinline__ float unmono(u32 h) {
    const u32 b = (h & 0x80000000u) ? (h & 0x7FFFFFFFu) : ~h;
    return __uint_as_float(b);
}

// Cross-lane bitonic sort over the 64 lanes, ascending by lane index.
__device__ __forceinline__ u32 sort64_u32(u32 k, int lane) {
#pragma unroll
    for (int kk = 2; kk <= 64; kk <<= 1) {
#pragma unroll
        for (int j = kk >> 1; j > 0; j >>= 1) {
            const u32 o = __shfl_xor(k, j);
            const bool keep_min = (((lane & j) == 0) == ((lane & kk) == 0));
            const u32 mn = (k < o) ? k : o;
            const u32 mx = (k < o) ? o : k;
            k = keep_min ? mn : mx;
        }
    }
    return k;
}
__device__ __forceinline__ u64 sort64_u64(u64 k, int lane) {
#pragma unroll
    for (int kk = 2; kk <= 64; kk <<= 1) {
#pragma unroll
        for (int j = kk >> 1; j > 0; j >>= 1) {
            const u64 o = __shfl_xor(k, j);
            const bool keep_min = (((lane & j) == 0) == ((lane & kk) == 0));
            const u64 mn = (k < o) ? k : o;
            const u64 mx = (k < o) ? o : k;
            k = keep_min ? mn : mx;
        }
    }
    return k;
}

// REGC: number of leading iterations whose d2 is register-cached (<= total).
// TOTC > 0: compile-time total per-lane candidate count (packed fast path).
// TOTC == 0: generic runtime fallback (R8 two-pass, no cache).
template <int TOTC, int REGC>
__global__ __launch_bounds__(THREADS, 8) void knn_main(
    const float* __restrict__ x, const float4* __restrict__ yp,
    const float* __restrict__ y, const float* __restrict__ feat,
    const int* __restrict__ x_batch, float* __restrict__ out,
    int n, int per, int packed)
{
    __shared__ u64 list_s[BLK_WAVES][LIST_CAP];  // 32 KiB survivor lists
    __shared__ int cnt_s[BLK_WAVES];

    const int lane = (int)threadIdx.x & 63;
    const int wv   = (int)(threadIdx.x >> 6);
    const int i    = blockIdx.x * BLK_WAVES + wv;   // this wave's point
    if (i >= n) return;

    if (lane == 0) cnt_s[wv] = 0;   // own counter; same-wave DS is in-order

    const int b     = x_batch[i];                   // lane-uniform
    const int ybase = b * per;

    const float px0 = x[(size_t)i * 3 + 0];
    const float px1 = x[(size_t)i * 3 + 1];
    const float px2 = x[(size_t)i * 3 + 2];
    const float x2s = __fadd_rn(__fadd_rn(__fmul_rn(px0, px0), __fmul_rn(px1, px1)),
                                __fmul_rn(px2, px2));

    float thrf;

    if constexpr (TOTC > 0) {
        // ---- Phase A: d2 over candidates j = ybase + t*64 + lane.
        // First REGC iterations cached in registers; rest recomputed later.
        float d2c[REGC];
        float md = __builtin_inff();
#pragma unroll
        for (int t = 0; t < REGC; ++t) {
            const float4 q = yp[ybase + t * 64 + lane];   // coalesced
            float dot = __fmaf_rn(px0, q.x, 0.0f);
            dot = __fmaf_rn(px1, q.y, dot);
            dot = __fmaf_rn(px2, q.z, dot);
            const float d2 = __fsub_rn(__fadd_rn(x2s, q.w), __fmul_rn(2.0f, dot));
            d2c[t] = d2;
            md = fminf(md, d2);
        }
#pragma unroll 4
        for (int t = REGC; t < TOTC; ++t) {
            const float4 q = yp[ybase + t * 64 + lane];
            float dot = __fmaf_rn(px0, q.x, 0.0f);
            dot = __fmaf_rn(px1, q.y, dot);
            dot = __fmaf_rn(px2, q.z, dot);
            const float d2 = __fsub_rn(__fadd_rn(x2s, q.w), __fmul_rn(2.0f, dot));
            md = fminf(md, d2);
        }

        // thr = 16th-smallest of the 64 lane-mins (exact d2 bits).
        const u32 sorted = sort64_u32(mono(md), lane);
        thrf = unmono(__shfl(sorted, 15));

        // ---- Phase B: cached half tested in-register; uncached half
        // recomputed (identical ops + inputs => identical bits).
#pragma unroll
        for (int t = 0; t < REGC; ++t) {
            if (d2c[t] <= thrf) {
                const int slot = atomicAdd(&cnt_s[wv], 1);
                if (slot < LIST_CAP)
                    list_s[wv][slot] =
                        ((u64)mono(d2c[t]) << 32) | (u32)(ybase + t * 64 + lane);
            }
        }
#pragma unroll 4
        for (int t = REGC; t < TOTC; ++t) {
            const float4 q = yp[ybase + t * 64 + lane];
            float dot = __fmaf_rn(px0, q.x, 0.0f);
            dot = __fmaf_rn(px1, q.y, dot);
            dot = __fmaf_rn(px2, q.z, dot);
            const float d2 = __fsub_rn(__fadd_rn(x2s, q.w), __fmul_rn(2.0f, dot));
            if (d2 <= thrf) {
                const int slot = atomicAdd(&cnt_s[wv], 1);
                if (slot < LIST_CAP)
                    list_s[wv][slot] =
                        ((u64)mono(d2) << 32) | (u32)(ybase + t * 64 + lane);
            }
        }
    } else {
        // Generic fallback: two-pass scan (R8 structure, unpacked y ok).
        const int iters = per / 64;
        float md = __builtin_inff();
        for (int t = 0; t < iters; ++t) {
            const int j = ybase + t * 64 + lane;
            float q0, q1, q2, qs;
            if (packed) {
                const float4 q = yp[j];
                q0 = q.x; q1 = q.y; q2 = q.z; qs = q.w;
            } else {
                q0 = y[(size_t)j * 3 + 0];
                q1 = y[(size_t)j * 3 + 1];
                q2 = y[(size_t)j * 3 + 2];
                qs = __fadd_rn(__fadd_rn(__fmul_rn(q0, q0), __fmul_rn(q1, q1)),
                               __fmul_rn(q2, q2));
            }
            float dot = __fmaf_rn(px0, q0, 0.0f);
            dot = __fmaf_rn(px1, q1, dot);
            dot = __fmaf_rn(px2, q2, dot);
            md = fminf(md, __fsub_rn(__fadd_rn(x2s, qs), __fmul_rn(2.0f, dot)));
        }
        const u32 sorted = sort64_u32(mono(md), lane);
        thrf = unmono(__shfl(sorted, 15));
        for (int t = 0; t < iters; ++t) {
            const int j = ybase + t * 64 + lane;
            float q0, q1, q2, qs;
            if (packed) {
                const float4 q = yp[j];
                q0 = q.x; q1 = q.y; q2 = q.z; qs = q.w;
            } else {
                q0 = y[(size_t)j * 3 + 0];
                q1 = y[(size_t)j * 3 + 1];
                q2 = y[(size_t)j * 3 + 2];
                qs = __fadd_rn(__fadd_rn(__fmul_rn(q0, q0), __fmul_rn(q1, q1)),
                               __fmul_rn(q2, q2));
            }
            float dot = __fmaf_rn(px0, q0, 0.0f);
            dot = __fmaf_rn(px1, q1, dot);
            dot = __fmaf_rn(px2, q2, dot);
            const float d2 = __fsub_rn(__fadd_rn(x2s, qs), __fmul_rn(2.0f, dot));
            if (d2 <= thrf) {
                const int slot = atomicAdd(&cnt_s[wv], 1);
                if (slot < LIST_CAP)
                    list_s[wv][slot] = ((u64)mono(d2) << 32) | (u32)j;
            }
        }
    }

    int S = *(volatile int*)&cnt_s[wv];             // same-wave DS in-order
    if (S > LIST_CAP) S = LIST_CAP;

    // ---- Phase C: top-16 via wave sort-64 (chunked for S > 64; exact).
    u64 k0 = (lane < S) ? list_s[wv][lane] : INF_KEY;
    u64 top = sort64_u64(k0, lane);
    for (int pos = 64; pos < S; pos += 48) {
        const int src = pos + lane - 16;
        const u64 k = (lane < 16) ? top
                                  : ((src < S) ? list_s[wv][src] : INF_KEY);
        top = sort64_u64(k, lane);
    }

    // ---- Gather + mean, all 64 lanes: rank = lane&15, chunk = lane>>4.
    const int r = lane & 15;
    const int c = lane >> 4;
    const u64 krank = __shfl(top, r);               // rank-r key (lanes 0..15)
    const int gidx  = (int)(u32)krank;              // global y index
    const float4 fq = ((const float4*)feat)[(size_t)gidx * 4 + c];
    float f0 = fq.x, f1 = fq.y, f2 = fq.z, f3 = fq.w;
#pragma unroll
    for (int mask = 1; mask <= 8; mask <<= 1) {     // sum over ranks in-group
        f0 = __fadd_rn(f0, __shfl_xor(f0, mask));
        f1 = __fadd_rn(f1, __shfl_xor(f1, mask));
        f2 = __fadd_rn(f2, __shfl_xor(f2, mask));
        f3 = __fadd_rn(f3, __shfl_xor(f3, mask));
    }
    if (r == 0) {
        float4* o4 = (float4*)out + (size_t)i * 4;
        o4[c] = make_float4(__fmul_rn(f0, 0.0625f), __fmul_rn(f1, 0.0625f),
                            __fmul_rn(f2, 0.0625f), __fmul_rn(f3, 0.0625f));
    }
}

extern "C" void kernel_launch(void* const* d_in, const int* in_sizes, int n_in,
                              void* d_out, int out_size, void* d_ws, size_t ws_size,
                              hipStream_t stream) {
    const float* x       = (const float*)d_in[0];
    const float* y       = (const float*)d_in[1];
    const float* feat    = (const float*)d_in[2];
    const int*   x_batch = (const int*)d_in[3];

    const int n   = in_sizes[0] / 3;   // 16384 query points
    const int m   = in_sizes[1] / 3;   // 16384 y points
    const int per = m / 8;             // 2048 per batch (N_BATCHES = 8)

    float* out = (float*)d_out;

    const size_t need = (size_t)m * sizeof(float4);
    const int packed = (ws_size >= need) ? 1 : 0;
    float4* yp = (float4*)d_ws;

    if (packed)
        knn_prep<<<(m + 255) / 256, 256, 0, stream>>>(y, yp, m);

    const int blocks = (n + BLK_WAVES - 1) / BLK_WAVES;   // 2048
    if (packed && per == 2048)
        knn_main<32, 16><<<blocks, THREADS, 0, stream>>>(x, yp, y, feat,
                                                         x_batch, out, n, per, packed);
    else
        knn_main<0, 0><<<blocks, THREADS, 0, stream>>>(x, yp, y, feat,
                                                       x_batch, out, n, per, packed);
}

// Round 11
// 41.667 us; speedup vs baseline: 4.0294x; 1.1673x over previous
//
#include <hip/hip_runtime.h>

// KNN (k=16) within batch-diagonal blocks + neighbor-feature mean-pool.
// N = 16384 points, 8 batches of 2048 (contiguous), FEAT = 16.
//
// R10 -> R11: R10 still spilled (WRITE 25MB, VGPR 32 under a 64 cap; true
// need ~70).
//  * __launch_bounds__(512,7): VGPR cap ~73 covers the need -> no spill;
//    7-8 waves/EU (87-100% of the LDS-allowed 32 waves/CU).
//  * Ballot-compaction append: __ballot + mbcnt prefix + wave-uniform
//    register count S. No LDS atomics, no volatile count read. Slot order
//    changes; keys get sorted in phase C, so selection is unchanged.
//  * Phase A min chain split into 2 independent accumulators (min is
//    exactly associative on non-NaN => identical bits, half the latency).
// Exactness machinery unchanged (9 passing rounds): reference-bit d2
// (FMA chain, rounded squares), thr = 16th-smallest of 64 lane-mins
// (provably valid), u64 (mono(d2)<<32|idx) keys == lax.top_k stable order,
// butterfly mean rounding relaxation (proven R4+).

typedef unsigned long long u64;
typedef unsigned int u32;

#define FEAT 16
#define BLK_WAVES 8
#define THREADS (BLK_WAVES * 64)   // 512
#define LIST_CAP 512
#define INF_KEY 0xFFFFFFFFFFFFFFFFull

__global__ void knn_prep(const float* __restrict__ y, float4* __restrict__ yp, int m)
{
    const int j = blockIdx.x * 256 + (int)threadIdx.x;
    if (j < m) {
        const float a0 = y[(size_t)j * 3 + 0];
        const float a1 = y[(size_t)j * 3 + 1];
        const float a2 = y[(size_t)j * 3 + 2];
        const float s  = __fadd_rn(__fadd_rn(__fmul_rn(a0, a0), __fmul_rn(a1, a1)),
                                   __fmul_rn(a2, a2));
        yp[j] = make_float4(a0, a1, a2, s);
    }
}

__device__ __forceinline__ u32 mono(float f) {
    const u32 b = __float_as_uint(f);
    return b ^ (((u32)(((int)b) >> 31)) | 0x80000000u);
}
__device__ __forceinline__ float unmono(u32 h) {
    const u32 b = (h & 0x80000000u) ? (h & 0x7FFFFFFFu) : ~h;
    return __uint_as_float(b);
}
__device__ __forceinline__ int lanes_below(u64 mask) {
    return __builtin_amdgcn_mbcnt_hi((u32)(mask >> 32),
           __builtin_amdgcn_mbcnt_lo((u32)mask, 0));
}

// Cross-lane bitonic sort over the 64 lanes, ascending by lane index.
__device__ __forceinline__ u32 sort64_u32(u32 k, int lane) {
#pragma unroll
    for (int kk = 2; kk <= 64; kk <<= 1) {
#pragma unroll
        for (int j = kk >> 1; j > 0; j >>= 1) {
            const u32 o = __shfl_xor(k, j);
            const bool keep_min = (((lane & j) == 0) == ((lane & kk) == 0));
            const u32 mn = (k < o) ? k : o;
            const u32 mx = (k < o) ? o : k;
            k = keep_min ? mn : mx;
        }
    }
    return k;
}
__device__ __forceinline__ u64 sort64_u64(u64 k, int lane) {
#pragma unroll
    for (int kk = 2; kk <= 64; kk <<= 1) {
#pragma unroll
        for (int j = kk >> 1; j > 0; j >>= 1) {
            const u64 o = __shfl_xor(k, j);
            const bool keep_min = (((lane & j) == 0) == ((lane & kk) == 0));
            const u64 mn = (k < o) ? k : o;
            const u64 mx = (k < o) ? o : k;
            k = keep_min ? mn : mx;
        }
    }
    return k;
}

// REGC: leading iterations with register-cached d2. TOTC > 0: compile-time
// per-lane candidate count (packed fast path). TOTC == 0: runtime fallback.
template <int TOTC, int REGC>
__global__ __launch_bounds__(THREADS, 7) void knn_main(
    const float* __restrict__ x, const float4* __restrict__ yp,
    const float* __restrict__ y, const float* __restrict__ feat,
    const int* __restrict__ x_batch, float* __restrict__ out,
    int n, int per, int packed)
{
    __shared__ u64 list_s[BLK_WAVES][LIST_CAP];  // 32 KiB survivor lists

    const int lane = (int)threadIdx.x & 63;
    const int wv   = (int)(threadIdx.x >> 6);
    const int i    = blockIdx.x * BLK_WAVES + wv;   // this wave's point
    if (i >= n) return;

    const int b     = x_batch[i];                   // lane-uniform
    const int ybase = b * per;

    const float px0 = x[(size_t)i * 3 + 0];
    const float px1 = x[(size_t)i * 3 + 1];
    const float px2 = x[(size_t)i * 3 + 2];
    const float x2s = __fadd_rn(__fadd_rn(__fmul_rn(px0, px0), __fmul_rn(px1, px1)),
                                __fmul_rn(px2, px2));

    float thrf;
    int S = 0;                                      // wave-uniform count

    if constexpr (TOTC > 0) {
        // ---- Phase A: d2 over candidates j = ybase + t*64 + lane.
        float d2c[REGC];
        float md0 = __builtin_inff(), md1 = __builtin_inff();
#pragma unroll
        for (int t = 0; t < REGC; ++t) {
            const float4 q = yp[ybase + t * 64 + lane];   // coalesced
            float dot = __fmaf_rn(px0, q.x, 0.0f);
            dot = __fmaf_rn(px1, q.y, dot);
            dot = __fmaf_rn(px2, q.z, dot);
            const float d2 = __fsub_rn(__fadd_rn(x2s, q.w), __fmul_rn(2.0f, dot));
            d2c[t] = d2;
            if (t & 1) md1 = fminf(md1, d2); else md0 = fminf(md0, d2);
        }
#pragma unroll 4
        for (int t = REGC; t < TOTC; ++t) {
            const float4 q = yp[ybase + t * 64 + lane];
            float dot = __fmaf_rn(px0, q.x, 0.0f);
            dot = __fmaf_rn(px1, q.y, dot);
            dot = __fmaf_rn(px2, q.z, dot);
            const float d2 = __fsub_rn(__fadd_rn(x2s, q.w), __fmul_rn(2.0f, dot));
            if (t & 1) md1 = fminf(md1, d2); else md0 = fminf(md0, d2);
        }
        const float md = fminf(md0, md1);

        // thr = 16th-smallest of the 64 lane-mins (exact d2 bits).
        const u32 sorted = sort64_u32(mono(md), lane);
        thrf = unmono(__shfl(sorted, 15));

        // ---- Phase B: ballot-compacted append (no atomics).
#pragma unroll
        for (int t = 0; t < REGC; ++t) {
            const bool pred = (d2c[t] <= thrf);
            const u64 mask = __ballot(pred);
            if (pred) {
                const int slot = S + lanes_below(mask);
                if (slot < LIST_CAP)
                    list_s[wv][slot] =
                        ((u64)mono(d2c[t]) << 32) | (u32)(ybase + t * 64 + lane);
            }
            S += __popcll(mask);
        }
#pragma unroll 4
        for (int t = REGC; t < TOTC; ++t) {
            const float4 q = yp[ybase + t * 64 + lane];
            float dot = __fmaf_rn(px0, q.x, 0.0f);
            dot = __fmaf_rn(px1, q.y, dot);
            dot = __fmaf_rn(px2, q.z, dot);
            const float d2 = __fsub_rn(__fadd_rn(x2s, q.w), __fmul_rn(2.0f, dot));
            const bool pred = (d2 <= thrf);
            const u64 mask = __ballot(pred);
            if (pred) {
                const int slot = S + lanes_below(mask);
                if (slot < LIST_CAP)
                    list_s[wv][slot] =
                        ((u64)mono(d2) << 32) | (u32)(ybase + t * 64 + lane);
            }
            S += __popcll(mask);
        }
    } else {
        // Generic fallback: two-pass scan (R8 structure, unpacked y ok).
        const int iters = per / 64;
        float md = __builtin_inff();
        for (int t = 0; t < iters; ++t) {
            const int j = ybase + t * 64 + lane;
            float q0, q1, q2, qs;
            if (packed) {
                const float4 q = yp[j];
                q0 = q.x; q1 = q.y; q2 = q.z; qs = q.w;
            } else {
                q0 = y[(size_t)j * 3 + 0];
                q1 = y[(size_t)j * 3 + 1];
                q2 = y[(size_t)j * 3 + 2];
                qs = __fadd_rn(__fadd_rn(__fmul_rn(q0, q0), __fmul_rn(q1, q1)),
                               __fmul_rn(q2, q2));
            }
            float dot = __fmaf_rn(px0, q0, 0.0f);
            dot = __fmaf_rn(px1, q1, dot);
            dot = __fmaf_rn(px2, q2, dot);
            md = fminf(md, __fsub_rn(__fadd_rn(x2s, qs), __fmul_rn(2.0f, dot)));
        }
        const u32 sorted = sort64_u32(mono(md), lane);
        thrf = unmono(__shfl(sorted, 15));
        for (int t = 0; t < iters; ++t) {
            const int j = ybase + t * 64 + lane;
            float q0, q1, q2, qs;
            if (packed) {
                const float4 q = yp[j];
                q0 = q.x; q1 = q.y; q2 = q.z; qs = q.w;
            } else {
                q0 = y[(size_t)j * 3 + 0];
                q1 = y[(size_t)j * 3 + 1];
                q2 = y[(size_t)j * 3 + 2];
                qs = __fadd_rn(__fadd_rn(__fmul_rn(q0, q0), __fmul_rn(q1, q1)),
                               __fmul_rn(q2, q2));
            }
            float dot = __fmaf_rn(px0, q0, 0.0f);
            dot = __fmaf_rn(px1, q1, dot);
            dot = __fmaf_rn(px2, q2, dot);
            const float d2 = __fsub_rn(__fadd_rn(x2s, qs), __fmul_rn(2.0f, dot));
            const bool pred = (d2 <= thrf);
            const u64 mask = __ballot(pred);
            if (pred) {
                const int slot = S + lanes_below(mask);
                if (slot < LIST_CAP)
                    list_s[wv][slot] = ((u64)mono(d2) << 32) | (u32)j;
            }
            S += __popcll(mask);
        }
    }

    if (S > LIST_CAP) S = LIST_CAP;

    // ---- Phase C: top-16 via wave sort-64 (chunked for S > 64; exact).
    u64 k0 = (lane < S) ? list_s[wv][lane] : INF_KEY;
    u64 top = sort64_u64(k0, lane);
    for (int pos = 64; pos < S; pos += 48) {
        const int src = pos + lane - 16;
        const u64 k = (lane < 16) ? top
                                  : ((src < S) ? list_s[wv][src] : INF_KEY);
        top = sort64_u64(k, lane);
    }

    // ---- Gather + mean, all 64 lanes: rank = lane&15, chunk = lane>>4.
    const int r = lane & 15;
    const int c = lane >> 4;
    const u64 krank = __shfl(top, r);               // rank-r key (lanes 0..15)
    const int gidx  = (int)(u32)krank;              // global y index
    const float4 fq = ((const float4*)feat)[(size_t)gidx * 4 + c];
    float f0 = fq.x, f1 = fq.y, f2 = fq.z, f3 = fq.w;
#pragma unroll
    for (int mask = 1; mask <= 8; mask <<= 1) {     // sum over ranks in-group
        f0 = __fadd_rn(f0, __shfl_xor(f0, mask));
        f1 = __fadd_rn(f1, __shfl_xor(f1, mask));
        f2 = __fadd_rn(f2, __shfl_xor(f2, mask));
        f3 = __fadd_rn(f3, __shfl_xor(f3, mask));
    }
    if (r == 0) {
        float4* o4 = (float4*)out + (size_t)i * 4;
        o4[c] = make_float4(__fmul_rn(f0, 0.0625f), __fmul_rn(f1, 0.0625f),
                            __fmul_rn(f2, 0.0625f), __fmul_rn(f3, 0.0625f));
    }
}

extern "C" void kernel_launch(void* const* d_in, const int* in_sizes, int n_in,
                              void* d_out, int out_size, void* d_ws, size_t ws_size,
                              hipStream_t stream) {
    const float* x       = (const float*)d_in[0];
    const float* y       = (const float*)d_in[1];
    const float* feat    = (const float*)d_in[2];
    const int*   x_batch = (const int*)d_in[3];

    const int n   = in_sizes[0] / 3;   // 16384 query points
    const int m   = in_sizes[1] / 3;   // 16384 y points
    const int per = m / 8;             // 2048 per batch (N_BATCHES = 8)

    float* out = (float*)d_out;

    const size_t need = (size_t)m * sizeof(float4);
    const int packed = (ws_size >= need) ? 1 : 0;
    float4* yp = (float4*)d_ws;

    if (packed)
        knn_prep<<<(m + 255) / 256, 256, 0, stream>>>(y, yp, m);

    const int blocks = (n + BLK_WAVES - 1) / BLK_WAVES;   // 2048
    if (packed && per == 2048)
        knn_main<32, 16><<<blocks, THREADS, 0, stream>>>(x, yp, y, feat,
                                                         x_batch, out, n, per, packed);
    else
        knn_main<0, 0><<<blocks, THREADS, 0, stream>>>(x, yp, y, feat,
                                                       x_batch, out, n, per, packed);
}